// Round 5
// baseline (324.080 us; speedup 1.0000x reference)
//
#include <hip/hip_runtime.h>
#include <hip/hip_bf16.h>

#define NSAMP   480000
#define NFRAMES 3000
#define NFFT    400
#define NFREQ   201
#define NMELS   80
#define HOP     160
#define BATCH   64
#define TT      128
#define TBLK    24                                // ceil(3000/128)
#define SPANU   20736                             // (TT-1)*HOP + 416 bf16 samples
#define NFRAG   26
#define KSTEPS  13
#define MKSTEPS 7
#define PWS     232                               // pw row stride (ushorts)
#define BCHUNK  512                               // ushorts per nf-chunk (64 lanes x 16B)
#define BTILE   (NFRAG * BCHUNK)                  // 13312 ushorts per B K-tile
#define LDS_B0  SPANU                             // B buffers after span
#define LDS_TOT (SPANU + 2 * BTILE)               // 47360 ushorts = 94720 B
#define FEAT_ELEMS (BATCH * NMELS * NFRAMES)
#define OUT_ELEMS  (FEAT_ELEMS + BATCH * NFRAMES)
#define TWO_PI  6.283185307179586f
#define WFRAG_ELEMS (NFRAG * KSTEPS * 64 * 8)     // 173056
#define MFRAG_ELEMS (5 * MKSTEPS * 64 * 8)        // 17920
#define WFRAG_BYTES (WFRAG_ELEMS * 2)
#define MFRAG_BYTES (MFRAG_ELEMS * 2)

typedef __attribute__((ext_vector_type(8))) short bf16x8;
typedef __attribute__((ext_vector_type(4))) float f32x4;

static __device__ __forceinline__ ushort f2bf(float x) {
    __hip_bfloat16 h = __float2bfloat16(x);
    return *reinterpret_cast<ushort*>(&h);
}

// async global->LDS, 16B per lane; LDS dest is wave-uniform base + lane*16 (HW).
static __device__ __forceinline__ void gld16(const ushort* g, ushort* l) {
    __builtin_amdgcn_global_load_lds(
        (const __attribute__((address_space(1))) unsigned int*)g,
        (__attribute__((address_space(3))) unsigned int*)l, 16, 0, 0);
}

// wfrag: B-frags of DFT W[k][n]; n=nf*16+(l&15) (even n: cos f=n/2, odd: -sin), k=ks*32+8*(l>>4)+j.
// mfrag: A-frags of MF^T: mel=Mf*16+(l&15), k=freq=ks*32+8*(l>>4)+j.
__global__ __launch_bounds__(256)
void fill_tables_k(ushort* __restrict__ wf, ushort* __restrict__ mfr,
                   const float* __restrict__ mf, unsigned* __restrict__ wmax) {
    const int t = blockIdx.x * 256 + threadIdx.x;
    if (t < WFRAG_ELEMS / 8) {
        const int lane = t & 63;
        const int fk = t >> 6;
        const int ks = fk % KSTEPS;
        const int nf = fk / KSTEPS;
        const int n = nf * 16 + (lane & 15);
        const int kbase = ks * 32 + 8 * (lane >> 4);
        #pragma unroll
        for (int j = 0; j < 8; ++j) {
            const int k = kbase + j;
            float val = 0.f;
            if (n < 2 * NFREQ && k < NFFT) {
                const int f = n >> 1;
                const float win = 0.5f - 0.5f * cosf(TWO_PI * (float)k / (float)NFFT);
                const int r = (f * k) % NFFT;
                const float ph = (float)r * (TWO_PI / (float)NFFT);
                float sv, cv;
                sincosf(ph, &sv, &cv);
                val = (n & 1) ? (-sv * win) : (cv * win);
            }
            wf[(size_t)t * 8 + j] = f2bf(val);
        }
    } else if (t < WFRAG_ELEMS / 8 + MFRAG_ELEMS / 8) {
        const int u = t - WFRAG_ELEMS / 8;
        const int lane = u & 63;
        const int fk = u >> 6;
        const int ks = fk % MKSTEPS;
        const int Mf = fk / MKSTEPS;
        const int mel = Mf * 16 + (lane & 15);
        const int kbase = ks * 32 + 8 * (lane >> 4);
        #pragma unroll
        for (int j = 0; j < 8; ++j) {
            const int freq = kbase + j;
            const float val = (freq < NFREQ) ? mf[freq * NMELS + mel] : 0.f;
            mfr[(size_t)u * 8 + j] = f2bf(val);
        }
    }
    if (blockIdx.x == 0 && threadIdx.x < BATCH) wmax[threadIdx.x] = 0u;
}

// 16 waves: wave wv stages chunk wv and (if wv<10) chunk wv+16.
static __device__ __forceinline__ void stageB(const ushort* __restrict__ wfrag,
                                              ushort* ldsB, int ks, int wv, int l) {
    gld16(wfrag + ((size_t)(wv * KSTEPS + ks) << 9) + (l << 3), ldsB + wv * BCHUNK);
    const int c1 = wv + 16;
    if (c1 < NFRAG)
        gld16(wfrag + ((size_t)(c1 * KSTEPS + ks) << 9) + (l << 3), ldsB + c1 * BCHUNK);
}

__global__ __launch_bounds__(1024, 4)
void stft_mel_mfma_k(const float* __restrict__ wav, const ushort* __restrict__ wfrag,
                     const ushort* __restrict__ mfrag,
                     float* __restrict__ out, unsigned* __restrict__ wmax) {
    __shared__ __align__(16) ushort lds[LDS_TOT];

    const int b   = blockIdx.y;
    const int t0  = blockIdx.x * TT;
    const int tid = threadIdx.x;
    const int l   = tid & 63;
    const int wv  = tid >> 6;                      // 0..15
    const int mw  = wv >> 2;                       // M-quarter (32 frames each)
    const int nw  = wv & 3;                        // N-set: nf = nw + 4i

    // Issue B-stage for ks=0 first: latency hides under span staging.
    stageB(wfrag, lds + LDS_B0, 0, wv, l);

    // Stage overlapped span as bf16 (4-wide packed ds_write_b64), inline reflect.
    const float* w = wav + (size_t)b * NSAMP;
    const int g0 = t0 * HOP - (NFFT / 2);
    for (int i = tid * 4; i < SPANU; i += 4096) {
        ushort4 v;
        #pragma unroll
        for (int j = 0; j < 4; ++j) {
            int idx = g0 + i + j;
            idx = (idx < 0) ? -idx : idx;
            idx = (idx >= NSAMP) ? (2 * NSAMP - 2 - idx) : idx;
            ((ushort*)&v)[j] = f2bf(w[idx]);
        }
        *reinterpret_cast<ushort4*>(&lds[i]) = v;
    }
    __syncthreads();   // drains span ds_writes AND stage(0) vmcnt

    f32x4 acc[7][2];
    #pragma unroll
    for (int i = 0; i < 7; ++i)
        #pragma unroll
        for (int m = 0; m < 2; ++m)
            acc[i][m] = (f32x4){0.f, 0.f, 0.f, 0.f};

    const ushort* aRow = lds + (mw * 32 + (l & 15)) * HOP + 8 * (l >> 4);
    int cur = 0;
    for (int ks = 0; ks < KSTEPS; ++ks) {
        if (ks + 1 < KSTEPS)
            stageB(wfrag, lds + LDS_B0 + (cur ^ 1) * BTILE, ks + 1, wv, l);
        const ushort* bbase = lds + LDS_B0 + cur * BTILE + (l << 3);
        const bf16x8 a0 = *reinterpret_cast<const bf16x8*>(aRow + ks * 32);
        const bf16x8 a1 = *reinterpret_cast<const bf16x8*>(aRow + 16 * HOP + ks * 32);
        #pragma unroll
        for (int i = 0; i < 7; ++i) {
            const int nf = nw + 4 * i;
            if (nf < NFRAG) {
                const bf16x8 bf = *reinterpret_cast<const bf16x8*>(bbase + nf * BCHUNK);
                acc[i][0] = __builtin_amdgcn_mfma_f32_16x16x32_bf16(a0, bf, acc[i][0], 0, 0, 0);
                acc[i][1] = __builtin_amdgcn_mfma_f32_16x16x32_bf16(a1, bf, acc[i][1], 0, 0, 0);
            }
        }
        __syncthreads();   // stage(ks+1) drained (overlapped by compute), buf swap safe
        cur ^= 1;
    }

    // pw[frame][freq] (bf16, stride PWS) aliases span+B0: all reads complete.
    // Zero mel-K padding cols (201..231).
    for (int i = tid; i < TT * 31; i += 1024) {
        const int r = i / 31;
        const int c = 201 + i - r * 31;
        lds[r * PWS + c] = 0;
    }
    // power = re^2+im^2 (adjacent lanes), scatter as bf16.
    #pragma unroll
    for (int i = 0; i < 7; ++i) {
        const int nf = nw + 4 * i;
        if (nf < NFRAG) {
            #pragma unroll
            for (int m = 0; m < 2; ++m) {
                const f32x4 v = acc[i][m];
                #pragma unroll
                for (int r = 0; r < 4; ++r) {
                    float p = v[r] * v[r];
                    p += __shfl_xor(p, 1);
                    if (!(l & 1)) {
                        const int f = 8 * nf + ((l & 15) >> 1);
                        const int fr = mw * 32 + 16 * m + 4 * (l >> 4) + r;
                        if (f < NFREQ) lds[fr * PWS + f] = f2bf(p);
                    }
                }
            }
        }
    }
    __syncthreads();

    // Mel GEMM: 40 tiles (Mf 0..4 x ff 0..7); wave wv takes tiles wv, wv+16, wv+32.
    float lmax = -3.0e38f;
    #pragma unroll
    for (int q = 0; q < 3; ++q) {
        const int tile = wv + 16 * q;
        if (tile < 40) {
            const int Mf = tile >> 3;
            const int ff = tile & 7;
            f32x4 mc = (f32x4){0.f, 0.f, 0.f, 0.f};
            #pragma unroll
            for (int ks = 0; ks < MKSTEPS; ++ks) {
                const bf16x8 aT = *reinterpret_cast<const bf16x8*>(
                    mfrag + ((size_t)(Mf * MKSTEPS + ks) * 64 + l) * 8);
                const bf16x8 bP = *reinterpret_cast<const bf16x8*>(
                    lds + (ff * 16 + (l & 15)) * PWS + 8 * (l >> 4) + 32 * ks);
                mc = __builtin_amdgcn_mfma_f32_16x16x32_bf16(aT, bP, mc, 0, 0, 0);
            }
            #pragma unroll
            for (int r = 0; r < 4; ++r) {
                const int mel = Mf * 16 + 4 * (l >> 4) + r;
                const int frame = t0 + ff * 16 + (l & 15);
                if (frame < NFRAMES) {
                    const float v = log10f(fmaxf(mc[r], 1e-10f));
                    out[((size_t)b * NMELS + mel) * NFRAMES + frame] = v;
                    lmax = fmaxf(lmax, v);
                }
            }
        }
    }

    #pragma unroll
    for (int off = 32; off > 0; off >>= 1)
        lmax = fmaxf(lmax, __shfl_xor(lmax, off));
    if (l == 0) {
        const unsigned bits = __float_as_uint(lmax);
        const unsigned key = bits ^ ((bits & 0x80000000u) ? 0xFFFFFFFFu : 0x80000000u);
        atomicMax(&wmax[b], key);
    }
}

__global__ __launch_bounds__(256)
void finalize_k(float* __restrict__ out, const unsigned* __restrict__ wmax,
                const int* __restrict__ valid) {
    const int i = blockIdx.x * 256 + threadIdx.x;
    if (i < FEAT_ELEMS) {
        const int b = i / (NMELS * NFRAMES);
        const unsigned key = wmax[b];
        const unsigned bits = key ^ ((key & 0x80000000u) ? 0x80000000u : 0xFFFFFFFFu);
        const float mx = __uint_as_float(bits);
        float v = out[i];
        v = fmaxf(v, mx - 8.0f);
        out[i] = (v + 4.0f) * 0.25f;
    } else if (i < OUT_ELEMS) {
        const int j = i - FEAT_ELEMS;
        const int bb = j / NFRAMES;
        const int tf = j - bb * NFRAMES;
        out[i] = (tf * HOP < valid[bb]) ? 1.0f : 0.0f;
    }
}

extern "C" void kernel_launch(void* const* d_in, const int* in_sizes, int n_in,
                              void* d_out, int out_size, void* d_ws, size_t ws_size,
                              hipStream_t stream) {
    const float* wav   = (const float*)d_in[0];
    const int*   valid = (const int*)d_in[1];
    const float* mf    = (const float*)d_in[2];
    float* out = (float*)d_out;

    ushort*   wfrag = (ushort*)d_ws;
    ushort*   mfrag = (ushort*)((char*)d_ws + WFRAG_BYTES);
    unsigned* wmax  = (unsigned*)((char*)d_ws + WFRAG_BYTES + MFRAG_BYTES);

    const int fill_items = WFRAG_ELEMS / 8 + MFRAG_ELEMS / 8;
    fill_tables_k<<<(fill_items + 255) / 256, 256, 0, stream>>>(wfrag, mfrag, mf, wmax);
    dim3 g(TBLK, BATCH);
    stft_mel_mfma_k<<<g, 1024, 0, stream>>>(wav, wfrag, mfrag, out, wmax);
    finalize_k<<<(OUT_ELEMS + 255) / 256, 256, 0, stream>>>(out, wmax, valid);
}

// Round 6
// 289.548 us; speedup vs baseline: 1.1193x; 1.1193x over previous
//
#include <hip/hip_runtime.h>
#include <hip/hip_bf16.h>

#define NSAMP   480000
#define NFRAMES 3000
#define NFFT    400
#define NFREQ   201
#define NMELS   80
#define HOP     160
#define BATCH   64
#define TT      64
#define TBLK    47                                // ceil(3000/64)
#define SPANU   10496                             // (TT-1)*HOP + 416 bf16 samples
#define NFRAG   26
#define KSTEPS  13
#define QCH     2                                 // K-steps per staged chunk
#define NCHUNK  7                                 // ceil(13/2)
#define MKSTEPS 7
#define PWS     232                               // pw row stride (ushorts)
#define BBUF    (NFRAG * QCH * 512)               // 26624 ush = 52 KB single B buffer
#define LDS_B0  SPANU
#define LDS_PW  SPANU                             // pw aliases B buffer after K-loop
#define LDS_TOT (SPANU + BBUF)                    // 37120 ush = 74240 B -> 2 blocks/CU
#define FEAT_ELEMS (BATCH * NMELS * NFRAMES)
#define OUT_ELEMS  (FEAT_ELEMS + BATCH * NFRAMES)
#define TWO_PI  6.283185307179586f
#define WFRAG_ELEMS (NFRAG * KSTEPS * 64 * 8)     // 173056
#define MFRAG_ELEMS (5 * MKSTEPS * 64 * 8)        // 17920
#define WFRAG_BYTES (WFRAG_ELEMS * 2)
#define MFRAG_BYTES (MFRAG_ELEMS * 2)

typedef __attribute__((ext_vector_type(8))) short bf16x8;
typedef __attribute__((ext_vector_type(4))) float f32x4;

static __device__ __forceinline__ ushort f2bf(float x) {
    __hip_bfloat16 h = __float2bfloat16(x);
    return *reinterpret_cast<ushort*>(&h);
}

// async global->LDS, 16B per lane; LDS dest is wave-uniform base + lane*16 (HW).
static __device__ __forceinline__ void gld16(const ushort* g, ushort* l) {
    __builtin_amdgcn_global_load_lds(
        (const __attribute__((address_space(1))) unsigned int*)g,
        (__attribute__((address_space(3))) unsigned int*)l, 16, 0, 0);
}

// wfrag: B-frags of DFT W[k][n]; n=nf*16+(l&15) (even n: cos f=n/2, odd: -sin), k=ks*32+8*(l>>4)+j.
// mfrag: A-frags of MF^T: mel=Mf*16+(l&15), k=freq=ks*32+8*(l>>4)+j.
__global__ __launch_bounds__(256)
void fill_tables_k(ushort* __restrict__ wf, ushort* __restrict__ mfr,
                   const float* __restrict__ mf, unsigned* __restrict__ wmax) {
    const int t = blockIdx.x * 256 + threadIdx.x;
    if (t < WFRAG_ELEMS / 8) {
        const int lane = t & 63;
        const int fk = t >> 6;
        const int ks = fk % KSTEPS;
        const int nf = fk / KSTEPS;
        const int n = nf * 16 + (lane & 15);
        const int kbase = ks * 32 + 8 * (lane >> 4);
        #pragma unroll
        for (int j = 0; j < 8; ++j) {
            const int k = kbase + j;
            float val = 0.f;
            if (n < 2 * NFREQ && k < NFFT) {
                const int f = n >> 1;
                const float win = 0.5f - 0.5f * cosf(TWO_PI * (float)k / (float)NFFT);
                const int r = (f * k) % NFFT;
                const float ph = (float)r * (TWO_PI / (float)NFFT);
                float sv, cv;
                sincosf(ph, &sv, &cv);
                val = (n & 1) ? (-sv * win) : (cv * win);
            }
            wf[(size_t)t * 8 + j] = f2bf(val);
        }
    } else if (t < WFRAG_ELEMS / 8 + MFRAG_ELEMS / 8) {
        const int u = t - WFRAG_ELEMS / 8;
        const int lane = u & 63;
        const int fk = u >> 6;
        const int ks = fk % MKSTEPS;
        const int Mf = fk / MKSTEPS;
        const int mel = Mf * 16 + (lane & 15);
        const int kbase = ks * 32 + 8 * (lane >> 4);
        #pragma unroll
        for (int j = 0; j < 8; ++j) {
            const int freq = kbase + j;
            const float val = (freq < NFREQ) ? mf[freq * NMELS + mel] : 0.f;
            mfr[(size_t)u * 8 + j] = f2bf(val);
        }
    }
    if (blockIdx.x == 0 && threadIdx.x < BATCH) wmax[threadIdx.x] = 0u;
}

// Stage chunk c (K-steps c*2 .. c*2+nks-1) into the single B buffer.
static __device__ __forceinline__ void stageB(const ushort* __restrict__ wfrag,
                                              ushort* ldsB, int c, int wv, int l) {
    if (c < NCHUNK - 1) {
        #pragma unroll
        for (int j = 0; j < 7; ++j) {              // 52 chunk-slots over 8 waves
            const int s = wv + 8 * j;
            if (s < 2 * NFRAG) {
                const int nf = s >> 1, kk = s & 1;
                gld16(wfrag + ((size_t)(nf * KSTEPS + c * QCH + kk) << 9) + (l << 3),
                      ldsB + ((nf * QCH + kk) << 9));
            }
        }
    } else {
        #pragma unroll
        for (int j = 0; j < 4; ++j) {              // last chunk: ks=12 only, 26 slots
            const int s = wv + 8 * j;
            if (s < NFRAG)
                gld16(wfrag + ((size_t)(s * KSTEPS + 12) << 9) + (l << 3),
                      ldsB + ((s * QCH) << 9));
        }
    }
}

__global__ __launch_bounds__(512, 4)
void stft_mel_mfma_k(const float* __restrict__ wav, const ushort* __restrict__ wfrag,
                     const ushort* __restrict__ mfrag,
                     float* __restrict__ out, unsigned* __restrict__ wmax) {
    __shared__ __align__(16) ushort lds[LDS_TOT];

    const int b   = blockIdx.y;
    const int t0  = blockIdx.x * TT;
    const int tid = threadIdx.x;
    const int l   = tid & 63;
    const int wv  = tid >> 6;                      // 0..7
    const int mw  = wv >> 2;                       // M-half (frames 0-31 / 32-63)
    const int nw  = wv & 3;                        // N-set: nf = nw + 4i

    // Issue B-stage for chunk 0 first: latency hides under span staging.
    stageB(wfrag, lds + LDS_B0, 0, wv, l);

    // Stage overlapped span as bf16. Fast path (no reflect) for interior blocks.
    const float* w = wav + (size_t)b * NSAMP;
    const int g0 = t0 * HOP - (NFFT / 2);
    if (g0 >= 0 && g0 + SPANU <= NSAMP) {
        for (int i = tid * 4; i < SPANU; i += 2048) {
            const float4 v = *reinterpret_cast<const float4*>(w + g0 + i);
            ushort4 u;
            u.x = f2bf(v.x); u.y = f2bf(v.y); u.z = f2bf(v.z); u.w = f2bf(v.w);
            *reinterpret_cast<ushort4*>(&lds[i]) = u;
        }
    } else {
        for (int i = tid * 4; i < SPANU; i += 2048) {
            ushort4 u;
            #pragma unroll
            for (int j = 0; j < 4; ++j) {
                int idx = g0 + i + j;
                idx = (idx < 0) ? -idx : idx;
                idx = (idx >= NSAMP) ? (2 * NSAMP - 2 - idx) : idx;
                ((ushort*)&u)[j] = f2bf(w[idx]);
            }
            *reinterpret_cast<ushort4*>(&lds[i]) = u;
        }
    }
    __syncthreads();   // drains span ds_writes AND stage(0) vmcnt

    f32x4 acc[7][2];
    #pragma unroll
    for (int i = 0; i < 7; ++i)
        #pragma unroll
        for (int m = 0; m < 2; ++m)
            acc[i][m] = (f32x4){0.f, 0.f, 0.f, 0.f};

    const ushort* aRow = lds + (mw * 32 + (l & 15)) * HOP + 8 * (l >> 4);

    #pragma unroll
    for (int c = 0; c < NCHUNK; ++c) {
        const int nks = (c == NCHUNK - 1) ? 1 : QCH;
        #pragma unroll
        for (int kk = 0; kk < QCH; ++kk) {
            if (kk < nks) {
                const int ks = c * QCH + kk;
                const bf16x8 a0 = *reinterpret_cast<const bf16x8*>(aRow + ks * 32);
                const bf16x8 a1 = *reinterpret_cast<const bf16x8*>(aRow + 16 * HOP + ks * 32);
                #pragma unroll
                for (int i = 0; i < 7; ++i) {
                    const int nf = nw + 4 * i;
                    if (nf < NFRAG) {
                        const bf16x8 bf = *reinterpret_cast<const bf16x8*>(
                            lds + LDS_B0 + ((nf * QCH + kk) << 9) + (l << 3));
                        acc[i][0] = __builtin_amdgcn_mfma_f32_16x16x32_bf16(a0, bf, acc[i][0], 0, 0, 0);
                        acc[i][1] = __builtin_amdgcn_mfma_f32_16x16x32_bf16(a1, bf, acc[i][1], 0, 0, 0);
                    }
                }
            }
        }
        __syncthreads();                 // all readers done with buffer
        if (c < NCHUNK - 1) {
            stageB(wfrag, lds + LDS_B0, c + 1, wv, l);
            __syncthreads();             // staged writes landed
        }
    }

    // pw[frame][freq] (bf16, stride PWS) aliases B buffer; all B-reads complete.
    // Zero mel-K padding cols (201..223).
    for (int i = tid; i < TT * 23; i += 512) {
        const int r = i / 23;
        const int cc = 201 + i - r * 23;
        lds[LDS_PW + r * PWS + cc] = 0;
    }
    // power = re^2+im^2 (adjacent lanes), scatter as bf16.
    #pragma unroll
    for (int i = 0; i < 7; ++i) {
        const int nf = nw + 4 * i;
        if (nf < NFRAG) {
            #pragma unroll
            for (int m = 0; m < 2; ++m) {
                const f32x4 v = acc[i][m];
                #pragma unroll
                for (int r = 0; r < 4; ++r) {
                    float p = v[r] * v[r];
                    p += __shfl_xor(p, 1);
                    if (!(l & 1)) {
                        const int f = 8 * nf + ((l & 15) >> 1);
                        const int fr = mw * 32 + 16 * m + 4 * (l >> 4) + r;
                        if (f < NFREQ) lds[LDS_PW + fr * PWS + f] = f2bf(p);
                    }
                }
            }
        }
    }
    __syncthreads();

    // Mel GEMM: 20 tiles (Mf 0..4 x ff 0..3); wave wv takes tiles wv, wv+8, wv+16.
    float lmax = -3.0e38f;
    #pragma unroll
    for (int q = 0; q < 3; ++q) {
        const int tile = wv + 8 * q;
        if (tile < 20) {
            const int Mf = tile >> 2;
            const int ff = tile & 3;
            f32x4 mc = (f32x4){0.f, 0.f, 0.f, 0.f};
            #pragma unroll
            for (int ks = 0; ks < MKSTEPS; ++ks) {
                const bf16x8 aT = *reinterpret_cast<const bf16x8*>(
                    mfrag + ((size_t)(Mf * MKSTEPS + ks) * 64 + l) * 8);
                const bf16x8 bP = *reinterpret_cast<const bf16x8*>(
                    lds + LDS_PW + (ff * 16 + (l & 15)) * PWS + 8 * (l >> 4) + 32 * ks);
                mc = __builtin_amdgcn_mfma_f32_16x16x32_bf16(aT, bP, mc, 0, 0, 0);
            }
            #pragma unroll
            for (int r = 0; r < 4; ++r) {
                const int mel = Mf * 16 + 4 * (l >> 4) + r;
                const int frame = t0 + ff * 16 + (l & 15);
                if (frame < NFRAMES) {
                    const float v = log10f(fmaxf(mc[r], 1e-10f));
                    out[((size_t)b * NMELS + mel) * NFRAMES + frame] = v;
                    lmax = fmaxf(lmax, v);
                }
            }
        }
    }

    #pragma unroll
    for (int off = 32; off > 0; off >>= 1)
        lmax = fmaxf(lmax, __shfl_xor(lmax, off));
    if (l == 0) {
        const unsigned bits = __float_as_uint(lmax);
        const unsigned key = bits ^ ((bits & 0x80000000u) ? 0xFFFFFFFFu : 0x80000000u);
        atomicMax(&wmax[b], key);
    }
}

__global__ __launch_bounds__(256)
void finalize_k(float* __restrict__ out, const unsigned* __restrict__ wmax,
                const int* __restrict__ valid) {
    const int i = blockIdx.x * 256 + threadIdx.x;
    if (i < FEAT_ELEMS) {
        const int b = i / (NMELS * NFRAMES);
        const unsigned key = wmax[b];
        const unsigned bits = key ^ ((key & 0x80000000u) ? 0x80000000u : 0xFFFFFFFFu);
        const float mx = __uint_as_float(bits);
        float v = out[i];
        v = fmaxf(v, mx - 8.0f);
        out[i] = (v + 4.0f) * 0.25f;
    } else if (i < OUT_ELEMS) {
        const int j = i - FEAT_ELEMS;
        const int bb = j / NFRAMES;
        const int tf = j - bb * NFRAMES;
        out[i] = (tf * HOP < valid[bb]) ? 1.0f : 0.0f;
    }
}

extern "C" void kernel_launch(void* const* d_in, const int* in_sizes, int n_in,
                              void* d_out, int out_size, void* d_ws, size_t ws_size,
                              hipStream_t stream) {
    const float* wav   = (const float*)d_in[0];
    const int*   valid = (const int*)d_in[1];
    const float* mf    = (const float*)d_in[2];
    float* out = (float*)d_out;

    ushort*   wfrag = (ushort*)d_ws;
    ushort*   mfrag = (ushort*)((char*)d_ws + WFRAG_BYTES);
    unsigned* wmax  = (unsigned*)((char*)d_ws + WFRAG_BYTES + MFRAG_BYTES);

    const int fill_items = WFRAG_ELEMS / 8 + MFRAG_ELEMS / 8;
    fill_tables_k<<<(fill_items + 255) / 256, 256, 0, stream>>>(wfrag, mfrag, mf, wmax);
    dim3 g(TBLK, BATCH);
    stft_mel_mfma_k<<<g, 512, 0, stream>>>(wav, wfrag, mfrag, out, wmax);
    finalize_k<<<(OUT_ELEMS + 255) / 256, 256, 0, stream>>>(out, wmax, valid);
}